// Round 6
// baseline (640.005 us; speedup 1.0000x reference)
//
#include <hip/hip_runtime.h>
#include <hip/hip_bf16.h>

// Shapes (fixed by setup_inputs): BC=128, H=4, N=1024, d=64, l=16, B=4, C=32,
// C_ch=32, TC=144, r=8. All float tensors are FLOAT32 (per reference).
typedef unsigned short ushort_t;

// ---------------- pq = slots[0] @ W^T, reshaped to [h][l][d] ----------------
// grid = 16 (one block per slot l), 256 threads (j = h*64+d)
__global__ __launch_bounds__(256) void k_pq(const float* __restrict__ slots,
                                            const float* __restrict__ W,
                                            float* __restrict__ pq) {
    int l = blockIdx.x, j = threadIdx.x;
    __shared__ float SL[256];
    SL[j] = slots[l * 256 + j];
    __syncthreads();
    const float4* wr = (const float4*)(W + j * 256);
    float acc = 0.f;
#pragma unroll 8
    for (int g = 0; g < 64; ++g) {
        float4 wv = wr[g];
        const float* sl = &SL[g * 4];
        acc += wv.x * sl[0] + wv.y * sl[1] + wv.z * sl[2] + wv.w * sl[3];
    }
    int h = j >> 6, d = j & 63;
    pq[(h * 16 + l) * 64 + d] = acc;
}

// ---------------- mu_flat[l][c*32+dd], mu_sqnorm[l] ----------------
__global__ void k_mu(const float* __restrict__ mu,
                     const int* __restrict__ cidx,
                     float* __restrict__ mu_flat,
                     float* __restrict__ mu_sq) {
    int l = blockIdx.x;            // 16 blocks
    __shared__ float U[256];       // [c][r] 32x8
    __shared__ float utu[64];
    int t = threadIdx.x;
    {
        int c = t >> 3, r = t & 7;
        U[t] = mu[(l * 144 + cidx[c]) * 8 + r];
    }
    __syncthreads();
#pragma unroll
    for (int i = 0; i < 4; ++i) {
        int e = t + i * 256;
        int c = e >> 5, dd = e & 31;
        float acc = 0.f;
#pragma unroll
        for (int r = 0; r < 8; ++r) acc += U[c * 8 + r] * U[dd * 8 + r];
        mu_flat[l * 1024 + e] = acc;
    }
    if (t < 64) {
        int r = t >> 3, s = t & 7;
        float acc = 0.f;
        for (int c = 0; c < 32; ++c) acc += U[c * 8 + r] * U[c * 8 + s];
        utu[t] = acc;
    }
    __syncthreads();
    if (t == 0) {
        float acc = 0.f;
        for (int i = 0; i < 64; ++i) acc += utu[i] * utu[i];
        mu_sq[l] = acc;
    }
}

// ---------------- dist[bs][l][n] ----------------
// grid = 1024: bs = blk>>8, chunk = blk&255. 256 threads = 4 waves; wave = one
// Ln row (n = chunk*4 + rid). Lane = (l = lane>>2, cs = lane&3): lane dots its
// c-quarter (256 elems) of Ln row against mu_flat row l; 2-step shfl_xor
// reduce over the 4 cs lanes. 16 waves/CU (was 4), deep load batching.
__global__ __launch_bounds__(256) void k_dist(const float* __restrict__ Ln,
                                              const float* __restrict__ mu_flat,
                                              const float* __restrict__ mu_sq,
                                              float* __restrict__ dist) {
    int blk = blockIdx.x;
    int chunk = blk & 255, bs = blk >> 8;
    int t = threadIdx.x;
    int rid = t >> 6, lane = t & 63;
    int l = lane >> 2, cs = lane & 3;
    int n = chunk * 4 + rid;
    const float4* L4 = (const float4*)(Ln + ((size_t)(bs * 1024 + n)) * 1024) + cs * 64;
    const float4* M4 = (const float4*)mu_flat + l * 256 + cs * 64;
    float cr = 0.f, lsq = 0.f;
#pragma unroll 8
    for (int i = 0; i < 64; ++i) {
        float4 lv = L4[i];
        float4 mv = M4[i];
        cr  += lv.x * mv.x + lv.y * mv.y + lv.z * mv.z + lv.w * mv.w;
        lsq += lv.x * lv.x + lv.y * lv.y + lv.z * lv.z + lv.w * lv.w;
    }
    cr  += __shfl_xor(cr, 1);  cr  += __shfl_xor(cr, 2);
    lsq += __shfl_xor(lsq, 1); lsq += __shfl_xor(lsq, 2);
    if (cs == 0) {
        float d2 = lsq + mu_sq[l] - 2.f * cr;
        dist[((size_t)(bs * 16 + l)) * 1024 + n] = sqrtf(fmaxf(d2, 0.f));
    }
}

// ---------------- scores -> exp (no max; bounded) -> pbuf, psum ----------------
// grid = bh*4+nq = 2048 blocks, 256 threads; thread = n = nq*256 + t.
// scores = 0.125*qk - beta*dist <= ~+0.03 (qk tiny, dist >= 0), so exp() is
// overflow-safe without max subtraction; softmax ratios are exact. Writes e
// (f32) to pbuf[bh][l][n] and 4-way partial sums to psum[bh][l][nq].
__global__ __launch_bounds__(256) void k_score(const float* __restrict__ kt,
                                               const float* __restrict__ pq,
                                               const float* __restrict__ dist,
                                               const float* __restrict__ beta_p,
                                               float* __restrict__ pbuf,
                                               float* __restrict__ psum) {
    int bx = blockIdx.x;
    int nq = bx & 3, bh = bx >> 2;
    int h = bh & 3;
    int bs = bh >> 7;                       // (bh>>2)>>5
    __shared__ __align__(16) float PQ[1024];
    __shared__ float wsum[64];              // [l][wave]
    int t = threadIdx.x;
    int lane = t & 63, w = t >> 6;          // 4 waves
    ((float4*)PQ)[t] = ((const float4*)(pq + h * 1024))[t & 255];
    float beta = beta_p[0];
    __syncthreads();

    int n = nq * 256 + t;
    const float4* kr = (const float4*)(kt + ((size_t)bh) * 65536 + (size_t)n * 64);
    float sc[16];
#pragma unroll
    for (int l = 0; l < 16; ++l) sc[l] = 0.f;
#pragma unroll
    for (int gb = 0; gb < 4; ++gb) {        // 4-deep K-load batches
        float4 kv0 = kr[gb * 4 + 0];
        float4 kv1 = kr[gb * 4 + 1];
        float4 kv2 = kr[gb * 4 + 2];
        float4 kv3 = kr[gb * 4 + 3];
#pragma unroll
        for (int l = 0; l < 16; ++l) {
            const float* p = &PQ[l * 64 + gb * 16];
            sc[l] += kv0.x * p[0]  + kv0.y * p[1]  + kv0.z * p[2]  + kv0.w * p[3]
                   + kv1.x * p[4]  + kv1.y * p[5]  + kv1.z * p[6]  + kv1.w * p[7]
                   + kv2.x * p[8]  + kv2.y * p[9]  + kv2.z * p[10] + kv2.w * p[11]
                   + kv3.x * p[12] + kv3.y * p[13] + kv3.z * p[14] + kv3.w * p[15];
        }
    }
#pragma unroll
    for (int l = 0; l < 16; ++l) {
        float e = __expf(0.125f * sc[l] - beta * dist[((size_t)(bs * 16 + l)) * 1024 + n]);
        sc[l] = e;
        pbuf[((size_t)(bh * 16 + l)) * 1024 + n] = e;
    }
    // partial sums: wave reduce then cross-wave (4 waves) via LDS
#pragma unroll
    for (int l = 0; l < 16; ++l) {
        float s = sc[l];
#pragma unroll
        for (int off = 32; off >= 1; off >>= 1) s += __shfl_xor(s, off);
        if (lane == 0) wsum[l * 4 + w] = s;
    }
    __syncthreads();
    if (t < 16)
        psum[((size_t)(bh * 16 + t)) * 4 + nq] =
            wsum[t * 4 + 0] + wsum[t * 4 + 1] + wsum[t * 4 + 2] + wsum[t * 4 + 3];
}

// ---------------- packed[l][d] = (sum_n e[l][n] v[n][d]) / S_l ----------------
// grid = 512 (bh), 1024 threads. Wave w: jg = w>>2 (n-quarter), lane ->
// (sl = (w&3)*4 + lane>>4, dg = lane&15). V read direct from global (16 unique
// float4/wave, lane-broadcast); p read as float4 (4 unique/wave). No barriers
// in the n-loop; cross-jg reduce via 16KB LDS, then normalize by S.
__global__ __launch_bounds__(1024) void k_pv(const float* __restrict__ vt,
                                             const float* __restrict__ pbuf,
                                             const float* __restrict__ psum,
                                             float* __restrict__ packed) {
    int bh = blockIdx.x;
    __shared__ __align__(16) float RED[4096];
    int t = threadIdx.x;
    int lane = t & 63, w = t >> 6;
    int jg = w >> 2;
    int sl = (w & 3) * 4 + (lane >> 4);
    int dg = lane & 15;
    const float4* pb4 = (const float4*)(pbuf + ((size_t)(bh * 16 + sl)) * 1024 + jg * 256);
    const float4* v4  = (const float4*)(vt + ((size_t)bh) * 65536) + (size_t)(jg * 256) * 16 + dg;
    float4 acc; acc.x = acc.y = acc.z = acc.w = 0.f;
    for (int rb = 0; rb < 32; ++rb) {       // 256 rows per quarter, 8 per batch
        float4 pA = pb4[rb * 2 + 0];
        float4 pB = pb4[rb * 2 + 1];
        float4 v0 = v4[(rb * 8 + 0) * 16];
        float4 v1 = v4[(rb * 8 + 1) * 16];
        float4 v2 = v4[(rb * 8 + 2) * 16];
        float4 v3 = v4[(rb * 8 + 3) * 16];
        float4 v5 = v4[(rb * 8 + 4) * 16];
        float4 v6 = v4[(rb * 8 + 5) * 16];
        float4 v7 = v4[(rb * 8 + 6) * 16];
        float4 v8 = v4[(rb * 8 + 7) * 16];
        acc.x += pA.x * v0.x + pA.y * v1.x + pA.z * v2.x + pA.w * v3.x
               + pB.x * v5.x + pB.y * v6.x + pB.z * v7.x + pB.w * v8.x;
        acc.y += pA.x * v0.y + pA.y * v1.y + pA.z * v2.y + pA.w * v3.y
               + pB.x * v5.y + pB.y * v6.y + pB.z * v7.y + pB.w * v8.y;
        acc.z += pA.x * v0.z + pA.y * v1.z + pA.z * v2.z + pA.w * v3.z
               + pB.x * v5.z + pB.y * v6.z + pB.z * v7.z + pB.w * v8.z;
        acc.w += pA.x * v0.w + pA.y * v1.w + pA.z * v2.w + pA.w * v3.w
               + pB.x * v5.w + pB.y * v6.w + pB.z * v7.w + pB.w * v8.w;
    }
    ((float4*)RED)[jg * 256 + sl * 16 + dg] = acc;   // float layout [jg][sl][d]
    __syncthreads();
    int l = t >> 6, d = t & 63;
    float S = psum[((size_t)(bh * 16 + l)) * 4 + 0] + psum[((size_t)(bh * 16 + l)) * 4 + 1]
            + psum[((size_t)(bh * 16 + l)) * 4 + 2] + psum[((size_t)(bh * 16 + l)) * 4 + 3];
    float sum = RED[l * 64 + d] + RED[1024 + l * 64 + d]
              + RED[2048 + l * 64 + d] + RED[3072 + l * 64 + d];
    packed[((size_t)bh) * 1024 + t] = sum / S;
}

// ---------------- processed = sdpa(packed, packed, packed) ----------------
__global__ void k_proc(const float* __restrict__ packed, float* __restrict__ proc) {
    int bh = blockIdx.x;           // 512 blocks
    __shared__ float P[1024];
    __shared__ float A[256];
    int t = threadIdx.x;
#pragma unroll
    for (int i = 0; i < 4; ++i) P[t + i * 256] = packed[(size_t)bh * 1024 + t + i * 256];
    __syncthreads();
    {
        int i = t >> 4, j = t & 15;
        float acc = 0.f;
#pragma unroll
        for (int dd = 0; dd < 64; ++dd) acc += P[i * 64 + dd] * P[j * 64 + dd];
        A[t] = acc * 0.125f;
    }
    __syncthreads();
    if (t < 16) {
        float m = -1e30f;
#pragma unroll
        for (int j = 0; j < 16; ++j) m = fmaxf(m, A[t * 16 + j]);
        float s = 0.f;
#pragma unroll
        for (int j = 0; j < 16; ++j) { float e = __expf(A[t * 16 + j] - m); A[t * 16 + j] = e; s += e; }
        float inv = 1.f / s;
#pragma unroll
        for (int j = 0; j < 16; ++j) A[t * 16 + j] *= inv;
    }
    __syncthreads();
#pragma unroll
    for (int i = 0; i < 4; ++i) {
        int e = t + i * 256;
        int r = e >> 6, d = e & 63;
        float acc = 0.f;
#pragma unroll
        for (int j = 0; j < 16; ++j) acc += A[r * 16 + j] * P[j * 64 + d];
        proc[(size_t)bh * 1024 + e] = acc;
    }
}

// ---------------- out = sdpa(q, processed, processed) ----------------
// grid = bh*8+chunk = 4096 blocks, 256 threads. Quad-split: 4 lanes per row
// (16 cols each), 2 rows per thread -> P b128 reads amortized over 2 rows;
// q loads / out stores are one full 64B line per lane.
__global__ __launch_bounds__(256) void k_final(const float* __restrict__ qt,
                                               const float* __restrict__ proc,
                                               float* __restrict__ out) {
    int bh = blockIdx.x >> 3, chunk = blockIdx.x & 7;
    __shared__ __align__(16) float P[1024];
    int t = threadIdx.x;
    ((float4*)P)[t] = ((const float4*)(proc + (size_t)bh * 1024))[t];
    __syncthreads();
    int q = t & 3, rid = t >> 2;
    int n0 = chunk * 128 + rid, n1 = n0 + 64;
    const float4* q0 = (const float4*)(qt + ((size_t)bh * 1024 + n0) * 64) + q * 4;
    const float4* q1 = (const float4*)(qt + ((size_t)bh * 1024 + n1) * 64) + q * 4;
    float4 qa0 = q0[0], qa1 = q0[1], qa2 = q0[2], qa3 = q0[3];
    float4 qb0 = q1[0], qb1 = q1[1], qb2 = q1[2], qb3 = q1[3];
    const float4* P4 = (const float4*)P + q * 4;

    float s0[16], s1[16];
#pragma unroll
    for (int j = 0; j < 16; ++j) {
        float4 p0 = P4[j * 16 + 0], p1 = P4[j * 16 + 1];
        float4 p2 = P4[j * 16 + 2], p3 = P4[j * 16 + 3];
        float a = qa0.x * p0.x + qa0.y * p0.y + qa0.z * p0.z + qa0.w * p0.w
                + qa1.x * p1.x + qa1.y * p1.y + qa1.z * p1.z + qa1.w * p1.w
                + qa2.x * p2.x + qa2.y * p2.y + qa2.z * p2.z + qa2.w * p2.w
                + qa3.x * p3.x + qa3.y * p3.y + qa3.z * p3.z + qa3.w * p3.w;
        float b = qb0.x * p0.x + qb0.y * p0.y + qb0.z * p0.z + qb0.w * p0.w
                + qb1.x * p1.x + qb1.y * p1.y + qb1.z * p1.z + qb1.w * p1.w
                + qb2.x * p2.x + qb2.y * p2.y + qb2.z * p2.z + qb2.w * p2.w
                + qb3.x * p3.x + qb3.y * p3.y + qb3.z * p3.z + qb3.w * p3.w;
        a += __shfl_xor(a, 1); a += __shfl_xor(a, 2);   // reduce over quad
        b += __shfl_xor(b, 1); b += __shfl_xor(b, 2);
        s0[j] = a * 0.125f; s1[j] = b * 0.125f;
    }
    // softmax over 16 keys, per row (replicated across the quad)
    float m0 = s0[0], m1 = s1[0];
#pragma unroll
    for (int j = 1; j < 16; ++j) { m0 = fmaxf(m0, s0[j]); m1 = fmaxf(m1, s1[j]); }
    float t0 = 0.f, t1 = 0.f;
#pragma unroll
    for (int j = 0; j < 16; ++j) {
        s0[j] = __expf(s0[j] - m0); t0 += s0[j];
        s1[j] = __expf(s1[j] - m1); t1 += s1[j];
    }
    float i0 = 1.f / t0, i1 = 1.f / t1;
#pragma unroll
    for (int j = 0; j < 16; ++j) { s0[j] *= i0; s1[j] *= i1; }

    float4 o00, o01, o02, o03, o10, o11, o12, o13;
    o00.x=o00.y=o00.z=o00.w=0.f; o01=o00; o02=o00; o03=o00;
    o10=o00; o11=o00; o12=o00; o13=o00;
#pragma unroll
    for (int j = 0; j < 16; ++j) {
        float4 p0 = P4[j * 16 + 0], p1 = P4[j * 16 + 1];
        float4 p2 = P4[j * 16 + 2], p3 = P4[j * 16 + 3];
        float a = s0[j], b = s1[j];
        o00.x += a * p0.x; o00.y += a * p0.y; o00.z += a * p0.z; o00.w += a * p0.w;
        o01.x += a * p1.x; o01.y += a * p1.y; o01.z += a * p1.z; o01.w += a * p1.w;
        o02.x += a * p2.x; o02.y += a * p2.y; o02.z += a * p2.z; o02.w += a * p2.w;
        o03.x += a * p3.x; o03.y += a * p3.y; o03.z += a * p3.z; o03.w += a * p3.w;
        o10.x += b * p0.x; o10.y += b * p0.y; o10.z += b * p0.z; o10.w += b * p0.w;
        o11.x += b * p1.x; o11.y += b * p1.y; o11.z += b * p1.z; o11.w += b * p1.w;
        o12.x += b * p2.x; o12.y += b * p2.y; o12.z += b * p2.z; o12.w += b * p2.w;
        o13.x += b * p3.x; o13.y += b * p3.y; o13.z += b * p3.z; o13.w += b * p3.w;
    }
    float4* w0 = (float4*)(out + ((size_t)bh * 1024 + n0) * 64) + q * 4;
    float4* w1 = (float4*)(out + ((size_t)bh * 1024 + n1) * 64) + q * 4;
    w0[0] = o00; w0[1] = o01; w0[2] = o02; w0[3] = o03;
    w1[0] = o10; w1[1] = o11; w1[2] = o12; w1[3] = o13;
}

extern "C" void kernel_launch(void* const* d_in, const int* in_sizes, int n_in,
                              void* d_out, int out_size, void* d_ws, size_t ws_size,
                              hipStream_t stream) {
    const float* q     = (const float*)d_in[0];
    const float* k     = (const float*)d_in[1];
    const float* v     = (const float*)d_in[2];
    const float* Ln    = (const float*)d_in[3];
    const float* slots = (const float*)d_in[4];
    const float* W     = (const float*)d_in[5];
    const float* mu    = (const float*)d_in[6];
    const float* beta  = (const float*)d_in[7];
    const int* cidx    = (const int*)d_in[8];
    // d_in[9] is C (==32), hard-coded in kernels.

    float* ws     = (float*)d_ws;
    float* pq     = ws;                 //       0 ..    4096
    float* muf    = ws + 4096;          //    4096 ..   20480
    float* musq   = ws + 20480;         //   20480 ..   20496
    float* dist   = ws + 20496;         //   20496 ..   86032
    float* packed = ws + 86032;         //   86032 ..  610320
    float* proc   = ws + 610320;        //  610320 .. 1134608
    float* psum   = ws + 1134608;       // 1134608 .. 1167376  (512*16*4 f32)
    // pbuf: 512*16*1024 f32 = 32MB. Prefer workspace (if sized); otherwise
    // fall back to d_out (134MB raw; only truly written by k_final at the end,
    // and k_pv consumes pbuf strictly before k_final on the same stream).
    const size_t WS_NEEDED = (size_t)(1167376 + 8388608) * sizeof(float);
    float* pbuf   = (ws_size >= WS_NEEDED) ? (ws + 1167376) : (float*)d_out;

    k_pq   <<<16,   256, 0, stream>>>(slots, W, pq);
    k_mu   <<<16,   256, 0, stream>>>(mu, cidx, muf, musq);
    k_dist <<<1024, 256, 0, stream>>>(Ln, muf, musq, dist);
    k_score<<<2048, 256, 0, stream>>>(k, pq, dist, beta, pbuf, psum);
    k_pv   <<<512, 1024, 0, stream>>>(v, pbuf, psum, packed);
    k_proc <<<512,  256, 0, stream>>>(packed, proc);
    k_final<<<4096, 256, 0, stream>>>(q, proc, (float*)d_out);
}

// Round 7
// 584.015 us; speedup vs baseline: 1.0959x; 1.0959x over previous
//
#include <hip/hip_runtime.h>
#include <hip/hip_bf16.h>

// Shapes (fixed by setup_inputs): BC=128, H=4, N=1024, d=64, l=16, B=4, C=32,
// C_ch=32, TC=144, r=8. All float tensors are FLOAT32 (per reference).
typedef unsigned short ushort_t;

// ---------------- pq = slots[0] @ W^T, reshaped to [h][l][d] ----------------
// grid = 16 (one block per slot l), 256 threads (j = h*64+d)
__global__ __launch_bounds__(256) void k_pq(const float* __restrict__ slots,
                                            const float* __restrict__ W,
                                            float* __restrict__ pq) {
    int l = blockIdx.x, j = threadIdx.x;
    __shared__ float SL[256];
    SL[j] = slots[l * 256 + j];
    __syncthreads();
    const float4* wr = (const float4*)(W + j * 256);
    float acc = 0.f;
#pragma unroll 8
    for (int g = 0; g < 64; ++g) {
        float4 wv = wr[g];
        const float* sl = &SL[g * 4];
        acc += wv.x * sl[0] + wv.y * sl[1] + wv.z * sl[2] + wv.w * sl[3];
    }
    int h = j >> 6, d = j & 63;
    pq[(h * 16 + l) * 64 + d] = acc;
}

// ---------------- mu_flat[l][c*32+dd], mu_sqnorm[l] ----------------
__global__ void k_mu(const float* __restrict__ mu,
                     const int* __restrict__ cidx,
                     float* __restrict__ mu_flat,
                     float* __restrict__ mu_sq) {
    int l = blockIdx.x;            // 16 blocks
    __shared__ float U[256];       // [c][r] 32x8
    __shared__ float utu[64];
    int t = threadIdx.x;
    {
        int c = t >> 3, r = t & 7;
        U[t] = mu[(l * 144 + cidx[c]) * 8 + r];
    }
    __syncthreads();
#pragma unroll
    for (int i = 0; i < 4; ++i) {
        int e = t + i * 256;
        int c = e >> 5, dd = e & 31;
        float acc = 0.f;
#pragma unroll
        for (int r = 0; r < 8; ++r) acc += U[c * 8 + r] * U[dd * 8 + r];
        mu_flat[l * 1024 + e] = acc;
    }
    if (t < 64) {
        int r = t >> 3, s = t & 7;
        float acc = 0.f;
        for (int c = 0; c < 32; ++c) acc += U[c * 8 + r] * U[c * 8 + s];
        utu[t] = acc;
    }
    __syncthreads();
    if (t == 0) {
        float acc = 0.f;
        for (int i = 0; i < 64; ++i) acc += utu[i] * utu[i];
        mu_sq[l] = acc;
    }
}

// ---------------- dist[bs][l][n] ----------------
// grid = 1024: bs = blk>>8, chunk = blk&255. 256 threads = 4 waves; wave = one
// Ln row (n = chunk*4 + rid). Lane = (l = lane>>2, cs = lane&3).
__global__ __launch_bounds__(256) void k_dist(const float* __restrict__ Ln,
                                              const float* __restrict__ mu_flat,
                                              const float* __restrict__ mu_sq,
                                              float* __restrict__ dist) {
    int blk = blockIdx.x;
    int chunk = blk & 255, bs = blk >> 8;
    int t = threadIdx.x;
    int rid = t >> 6, lane = t & 63;
    int l = lane >> 2, cs = lane & 3;
    int n = chunk * 4 + rid;
    const float4* L4 = (const float4*)(Ln + ((size_t)(bs * 1024 + n)) * 1024) + cs * 64;
    const float4* M4 = (const float4*)mu_flat + l * 256 + cs * 64;
    float cr = 0.f, lsq = 0.f;
#pragma unroll 8
    for (int i = 0; i < 64; ++i) {
        float4 lv = L4[i];
        float4 mv = M4[i];
        cr  += lv.x * mv.x + lv.y * mv.y + lv.z * mv.z + lv.w * mv.w;
        lsq += lv.x * lv.x + lv.y * lv.y + lv.z * lv.z + lv.w * lv.w;
    }
    cr  += __shfl_xor(cr, 1);  cr  += __shfl_xor(cr, 2);
    lsq += __shfl_xor(lsq, 1); lsq += __shfl_xor(lsq, 2);
    if (cs == 0) {
        float d2 = lsq + mu_sq[l] - 2.f * cr;
        dist[((size_t)(bs * 16 + l)) * 1024 + n] = sqrtf(fmaxf(d2, 0.f));
    }
}

// ---------------- scores -> exp (no max; bounded) -> pbuf, psum ----------------
// grid = bh*4+nq = 2048 blocks, 256 threads; thread = n = nq*256 + t.
// MLP: dist[16] prefetched up-front (coalesced, overlaps QK compute); K row
// loaded in two 8-deep float4 batches. launch_bounds(256,4) -> 128-VGPR cap.
__global__ __launch_bounds__(256, 4) void k_score(const float* __restrict__ kt,
                                                  const float* __restrict__ pq,
                                                  const float* __restrict__ dist,
                                                  const float* __restrict__ beta_p,
                                                  float* __restrict__ pbuf,
                                                  float* __restrict__ psum) {
    int bx = blockIdx.x;
    int nq = bx & 3, bh = bx >> 2;
    int h = bh & 3;
    int bs = bh >> 7;
    __shared__ __align__(16) float PQ[1024];
    __shared__ float wsum[64];              // [l][wave]
    int t = threadIdx.x;
    int lane = t & 63, w = t >> 6;          // 4 waves
    ((float4*)PQ)[t] = ((const float4*)(pq + h * 1024))[t & 255];
    float beta = beta_p[0];
    int n = nq * 256 + t;

    // prefetch dist (16 coalesced 256B wave-loads, consumed late)
    float dd[16];
#pragma unroll
    for (int l = 0; l < 16; ++l) dd[l] = dist[((size_t)(bs * 16 + l)) * 1024 + n];
    __syncthreads();

    const float4* kr = (const float4*)(kt + ((size_t)bh) * 65536 + (size_t)n * 64);
    float sc[16];
#pragma unroll
    for (int l = 0; l < 16; ++l) sc[l] = 0.f;
    float4 kv[8];
#pragma unroll
    for (int j = 0; j < 8; ++j) kv[j] = kr[j];          // 8 in flight
#pragma unroll
    for (int l = 0; l < 16; ++l) {
        const float* p = &PQ[l * 64];
        float s = 0.f;
#pragma unroll
        for (int j = 0; j < 8; ++j)
            s += kv[j].x * p[j*4] + kv[j].y * p[j*4+1] + kv[j].z * p[j*4+2] + kv[j].w * p[j*4+3];
        sc[l] = s;
    }
#pragma unroll
    for (int j = 0; j < 8; ++j) kv[j] = kr[8 + j];      // second batch
#pragma unroll
    for (int l = 0; l < 16; ++l) {
        const float* p = &PQ[l * 64 + 32];
        float s = sc[l];
#pragma unroll
        for (int j = 0; j < 8; ++j)
            s += kv[j].x * p[j*4] + kv[j].y * p[j*4+1] + kv[j].z * p[j*4+2] + kv[j].w * p[j*4+3];
        sc[l] = s;
    }
#pragma unroll
    for (int l = 0; l < 16; ++l) {
        float e = __expf(0.125f * sc[l] - beta * dd[l]);
        sc[l] = e;
        pbuf[((size_t)(bh * 16 + l)) * 1024 + n] = e;
    }
    // partial sums: wave reduce then cross-wave (4 waves) via LDS
#pragma unroll
    for (int l = 0; l < 16; ++l) {
        float s = sc[l];
#pragma unroll
        for (int off = 32; off >= 1; off >>= 1) s += __shfl_xor(s, off);
        if (lane == 0) wsum[l * 4 + w] = s;
    }
    __syncthreads();
    if (t < 16)
        psum[((size_t)(bh * 16 + t)) * 4 + nq] =
            wsum[t * 4 + 0] + wsum[t * 4 + 1] + wsum[t * 4 + 2] + wsum[t * 4 + 3];
}

// ---------------- pp[bh][ng][l][d] = sum over n-quarter of e[l][n] v[n][d] ----
// grid = bh*4+ng = 2048 blocks, 256 threads = 4 waves, launch_bounds(256,4):
// 4 blocks/CU, 128-VGPR cap. P-tile [16][256] staged coalesced in LDS. Wave w
// covers rows w*64..+63 of the quarter: V loaded 4-rows-per-instruction
// (lane=(sg,dg): fully-coalesced 1KB), 2-deep pipelined; acc[16] float4
// (static-indexed). shfl_xor(16/32) reduces row-subgroups; cross-wave via LDS.
__global__ __launch_bounds__(256, 4) void k_pv(const float* __restrict__ vt,
                                               const float* __restrict__ pbuf,
                                               float* __restrict__ pp) {
    int bx = blockIdx.x;
    int ng = bx & 3, bh = bx >> 2;
    __shared__ __align__(16) float PT[16 * 256];   // 16KB p tile
    __shared__ __align__(16) float RED[4 * 1024];  // 16KB cross-wave reduce
    int t = threadIdx.x;
    int lane = t & 63, w = t >> 6;
    // stage P tile (coalesced)
#pragma unroll
    for (int i = 0; i < 4; ++i) {
        int e4 = t + i * 256;
        ((float4*)PT)[e4] =
            ((const float4*)pbuf)[((size_t)(bh * 16 + (e4 >> 6))) * 256 + ng * 64 + (e4 & 63)];
    }
    __syncthreads();

    int sg = lane >> 4, dg = lane & 15;
    int R0 = ng * 256 + w * 64;
    const float4* vb = (const float4*)vt + (size_t)bh * 16384;
    float4 acc[16];
#pragma unroll
    for (int sl = 0; sl < 16; ++sl) { acc[sl].x = acc[sl].y = acc[sl].z = acc[sl].w = 0.f; }

    float4 v0 = vb[(R0 + 0 * 4 + sg) * 16 + dg];
    float4 v1 = vb[(R0 + 1 * 4 + sg) * 16 + dg];
    for (int rg = 0; rg < 16; ++rg) {
        float4 v2;
        if (rg < 14) v2 = vb[(R0 + (rg + 2) * 4 + sg) * 16 + dg];
        const float* pr = &PT[w * 64 + rg * 4 + sg];
#pragma unroll
        for (int sl = 0; sl < 16; ++sl) {
            float p = pr[sl * 256];
            acc[sl].x += p * v0.x; acc[sl].y += p * v0.y;
            acc[sl].z += p * v0.z; acc[sl].w += p * v0.w;
        }
        v0 = v1; v1 = v2;
    }
    // reduce over row-subgroups sg (lane bits 4,5)
#pragma unroll
    for (int sl = 0; sl < 16; ++sl) {
        acc[sl].x += __shfl_xor(acc[sl].x, 16); acc[sl].x += __shfl_xor(acc[sl].x, 32);
        acc[sl].y += __shfl_xor(acc[sl].y, 16); acc[sl].y += __shfl_xor(acc[sl].y, 32);
        acc[sl].z += __shfl_xor(acc[sl].z, 16); acc[sl].z += __shfl_xor(acc[sl].z, 32);
        acc[sl].w += __shfl_xor(acc[sl].w, 16); acc[sl].w += __shfl_xor(acc[sl].w, 32);
    }
    if (lane < 16) {
#pragma unroll
        for (int sl = 0; sl < 16; ++sl)
            ((float4*)RED)[w * 256 + sl * 16 + lane] = acc[sl];
    }
    __syncthreads();
    float4 s0 = ((float4*)RED)[t];
    float4 s1 = ((float4*)RED)[256 + t];
    float4 s2 = ((float4*)RED)[512 + t];
    float4 s3 = ((float4*)RED)[768 + t];
    float4 sum;
    sum.x = s0.x + s1.x + s2.x + s3.x;
    sum.y = s0.y + s1.y + s2.y + s3.y;
    sum.z = s0.z + s1.z + s2.z + s3.z;
    sum.w = s0.w + s1.w + s2.w + s3.w;
    ((float4*)pp)[(size_t)bx * 256 + t] = sum;
}

// ---------------- processed = sdpa(packed, packed, packed) ----------------
// Now also folds the 4-quarter pp sum + 1/S normalization into the P load.
__global__ void k_proc(const float* __restrict__ pp,
                       const float* __restrict__ psum,
                       float* __restrict__ proc) {
    int bh = blockIdx.x;           // 512 blocks
    __shared__ __align__(16) float P[1024];
    __shared__ float A[256];
    int t = threadIdx.x;
    {
        int sl = t >> 4;
        const float* ps = &psum[((size_t)(bh * 16 + sl)) * 4];
        float S = ps[0] + ps[1] + ps[2] + ps[3];
        float inv = 1.f / S;
        const float4* p4 = (const float4*)pp + (size_t)(bh * 4) * 256 + t;
        float4 a = p4[0], b = p4[256], c = p4[512], d = p4[768];
        float4 r;
        r.x = (a.x + b.x + c.x + d.x) * inv;
        r.y = (a.y + b.y + c.y + d.y) * inv;
        r.z = (a.z + b.z + c.z + d.z) * inv;
        r.w = (a.w + b.w + c.w + d.w) * inv;
        ((float4*)P)[t] = r;
    }
    __syncthreads();
    {
        int i = t >> 4, j = t & 15;
        float acc = 0.f;
#pragma unroll
        for (int dd = 0; dd < 64; ++dd) acc += P[i * 64 + dd] * P[j * 64 + dd];
        A[t] = acc * 0.125f;
    }
    __syncthreads();
    if (t < 16) {
        float m = -1e30f;
#pragma unroll
        for (int j = 0; j < 16; ++j) m = fmaxf(m, A[t * 16 + j]);
        float s = 0.f;
#pragma unroll
        for (int j = 0; j < 16; ++j) { float e = __expf(A[t * 16 + j] - m); A[t * 16 + j] = e; s += e; }
        float inv = 1.f / s;
#pragma unroll
        for (int j = 0; j < 16; ++j) A[t * 16 + j] *= inv;
    }
    __syncthreads();
#pragma unroll
    for (int i = 0; i < 4; ++i) {
        int e = t + i * 256;
        int r = e >> 6, d = e & 63;
        float acc = 0.f;
#pragma unroll
        for (int j = 0; j < 16; ++j) acc += A[r * 16 + j] * P[j * 64 + d];
        proc[(size_t)bh * 1024 + e] = acc;
    }
}

// ---------------- out = sdpa(q, processed, processed) ----------------
// grid = bh*8+chunk = 4096 blocks, 256 threads. Quad-split: 4 lanes per row
// (16 cols each), 2 rows per thread.
__global__ __launch_bounds__(256) void k_final(const float* __restrict__ qt,
                                               const float* __restrict__ proc,
                                               float* __restrict__ out) {
    int bh = blockIdx.x >> 3, chunk = blockIdx.x & 7;
    __shared__ __align__(16) float P[1024];
    int t = threadIdx.x;
    ((float4*)P)[t] = ((const float4*)(proc + (size_t)bh * 1024))[t];
    __syncthreads();
    int q = t & 3, rid = t >> 2;
    int n0 = chunk * 128 + rid, n1 = n0 + 64;
    const float4* q0 = (const float4*)(qt + ((size_t)bh * 1024 + n0) * 64) + q * 4;
    const float4* q1 = (const float4*)(qt + ((size_t)bh * 1024 + n1) * 64) + q * 4;
    float4 qa0 = q0[0], qa1 = q0[1], qa2 = q0[2], qa3 = q0[3];
    float4 qb0 = q1[0], qb1 = q1[1], qb2 = q1[2], qb3 = q1[3];
    const float4* P4 = (const float4*)P + q * 4;

    float s0[16], s1[16];
#pragma unroll
    for (int j = 0; j < 16; ++j) {
        float4 p0 = P4[j * 16 + 0], p1 = P4[j * 16 + 1];
        float4 p2 = P4[j * 16 + 2], p3 = P4[j * 16 + 3];
        float a = qa0.x * p0.x + qa0.y * p0.y + qa0.z * p0.z + qa0.w * p0.w
                + qa1.x * p1.x + qa1.y * p1.y + qa1.z * p1.z + qa1.w * p1.w
                + qa2.x * p2.x + qa2.y * p2.y + qa2.z * p2.z + qa2.w * p2.w
                + qa3.x * p3.x + qa3.y * p3.y + qa3.z * p3.z + qa3.w * p3.w;
        float b = qb0.x * p0.x + qb0.y * p0.y + qb0.z * p0.z + qb0.w * p0.w
                + qb1.x * p1.x + qb1.y * p1.y + qb1.z * p1.z + qb1.w * p1.w
                + qb2.x * p2.x + qb2.y * p2.y + qb2.z * p2.z + qb2.w * p2.w
                + qb3.x * p3.x + qb3.y * p3.y + qb3.z * p3.z + qb3.w * p3.w;
        a += __shfl_xor(a, 1); a += __shfl_xor(a, 2);   // reduce over quad
        b += __shfl_xor(b, 1); b += __shfl_xor(b, 2);
        s0[j] = a * 0.125f; s1[j] = b * 0.125f;
    }
    float m0 = s0[0], m1 = s1[0];
#pragma unroll
    for (int j = 1; j < 16; ++j) { m0 = fmaxf(m0, s0[j]); m1 = fmaxf(m1, s1[j]); }
    float t0 = 0.f, t1 = 0.f;
#pragma unroll
    for (int j = 0; j < 16; ++j) {
        s0[j] = __expf(s0[j] - m0); t0 += s0[j];
        s1[j] = __expf(s1[j] - m1); t1 += s1[j];
    }
    float i0 = 1.f / t0, i1 = 1.f / t1;
#pragma unroll
    for (int j = 0; j < 16; ++j) { s0[j] *= i0; s1[j] *= i1; }

    float4 o00, o01, o02, o03, o10, o11, o12, o13;
    o00.x=o00.y=o00.z=o00.w=0.f; o01=o00; o02=o00; o03=o00;
    o10=o00; o11=o00; o12=o00; o13=o00;
#pragma unroll
    for (int j = 0; j < 16; ++j) {
        float4 p0 = P4[j * 16 + 0], p1 = P4[j * 16 + 1];
        float4 p2 = P4[j * 16 + 2], p3 = P4[j * 16 + 3];
        float a = s0[j], b = s1[j];
        o00.x += a * p0.x; o00.y += a * p0.y; o00.z += a * p0.z; o00.w += a * p0.w;
        o01.x += a * p1.x; o01.y += a * p1.y; o01.z += a * p1.z; o01.w += a * p1.w;
        o02.x += a * p2.x; o02.y += a * p2.y; o02.z += a * p2.z; o02.w += a * p2.w;
        o03.x += a * p3.x; o03.y += a * p3.y; o03.z += a * p3.z; o03.w += a * p3.w;
        o10.x += b * p0.x; o10.y += b * p0.y; o10.z += b * p0.z; o10.w += b * p0.w;
        o11.x += b * p1.x; o11.y += b * p1.y; o11.z += b * p1.z; o11.w += b * p1.w;
        o12.x += b * p2.x; o12.y += b * p2.y; o12.z += b * p2.z; o12.w += b * p2.w;
        o13.x += b * p3.x; o13.y += b * p3.y; o13.z += b * p3.z; o13.w += b * p3.w;
    }
    float4* w0 = (float4*)(out + ((size_t)bh * 1024 + n0) * 64) + q * 4;
    float4* w1 = (float4*)(out + ((size_t)bh * 1024 + n1) * 64) + q * 4;
    w0[0] = o00; w0[1] = o01; w0[2] = o02; w0[3] = o03;
    w1[0] = o10; w1[1] = o11; w1[2] = o12; w1[3] = o13;
}

extern "C" void kernel_launch(void* const* d_in, const int* in_sizes, int n_in,
                              void* d_out, int out_size, void* d_ws, size_t ws_size,
                              hipStream_t stream) {
    const float* q     = (const float*)d_in[0];
    const float* k     = (const float*)d_in[1];
    const float* v     = (const float*)d_in[2];
    const float* Ln    = (const float*)d_in[3];
    const float* slots = (const float*)d_in[4];
    const float* W     = (const float*)d_in[5];
    const float* mu    = (const float*)d_in[6];
    const float* beta  = (const float*)d_in[7];
    const int* cidx    = (const int*)d_in[8];
    // d_in[9] is C (==32), hard-coded in kernels.

    float* ws     = (float*)d_ws;
    float* pq     = ws;                 //       0 ..    4096
    float* muf    = ws + 4096;          //    4096 ..   20480
    float* musq   = ws + 20480;         //   20480 ..   20496
    float* dist   = ws + 20496;         //   20496 ..   86032
    float* proc   = ws + 86032;         //   86032 ..  610320
    float* psum   = ws + 610320;        //  610320 ..  643088  (512*16*4)
    // pbuf (32MB) + pp (8MB): prefer workspace if sized; else stage in d_out
    // (134MB raw; k_score->k_pv->k_proc all complete before k_final writes it).
    const size_t WS_NEEDED = (size_t)(643088 + 8388608 + 2097152) * sizeof(float);
    float* pbuf, * pp;
    if (ws_size >= WS_NEEDED) {
        pbuf = ws + 643088;
        pp   = ws + 643088 + 8388608;
    } else {
        pbuf = (float*)d_out;
        pp   = (float*)d_out + 8388608;
    }

    k_pq   <<<16,   256, 0, stream>>>(slots, W, pq);
    k_mu   <<<16,   256, 0, stream>>>(mu, cidx, muf, musq);
    k_dist <<<1024, 256, 0, stream>>>(Ln, muf, musq, dist);
    k_score<<<2048, 256, 0, stream>>>(k, pq, dist, beta, pbuf, psum);
    k_pv   <<<2048, 256, 0, stream>>>(v, pbuf, pp);
    k_proc <<<512,  256, 0, stream>>>(pp, psum, proc);
    k_final<<<4096, 256, 0, stream>>>(q, proc, (float*)d_out);
}